// Round 1
// baseline (895.872 us; speedup 1.0000x reference)
//
#include <hip/hip_runtime.h>
#include <hip/hip_bf16.h>

#define QMAX 127.0f

typedef __bf16 bf16x4 __attribute__((ext_vector_type(4)));
typedef __bf16 bf16x8 __attribute__((ext_vector_type(8)));
typedef float  f32x4  __attribute__((ext_vector_type(4)));

// ws layout (bytes):
//   [0]    int  wmax_bits (atomicMax target)
//   [4]    int  bmax_bits
//   [16)   float qb[256]           (16 .. 1040)
//   [2048) __bf16 qw[256*256]      (2048 .. 133120)

__global__ void init_ws_kernel(int* ws) {
    ws[0] = 0;
    ws[1] = 0;
}

__global__ void absmax_kernel(const float* __restrict__ w,
                              const float* __restrict__ b,
                              int* __restrict__ wmax,
                              int* __restrict__ bmax) {
    __shared__ float red[4];
    const int tid = threadIdx.x;
    float v;
    if (blockIdx.x < 64) {
        // 64 blocks x 256 threads x float4 = 65536 floats
        float4 f = ((const float4*)w)[blockIdx.x * 256 + tid];
        v = fmaxf(fmaxf(fabsf(f.x), fabsf(f.y)), fmaxf(fabsf(f.z), fabsf(f.w)));
    } else {
        v = fabsf(b[tid]);
    }
    #pragma unroll
    for (int off = 32; off > 0; off >>= 1)
        v = fmaxf(v, __shfl_down(v, off, 64));
    if ((tid & 63) == 0) red[tid >> 6] = v;
    __syncthreads();
    if (tid == 0) {
        v = fmaxf(fmaxf(red[0], red[1]), fmaxf(red[2], red[3]));
        atomicMax(blockIdx.x < 64 ? wmax : bmax, __float_as_int(v));
    }
}

__global__ void quant_kernel(const float* __restrict__ w,
                             const float* __restrict__ b,
                             const int* __restrict__ maxes,
                             __bf16* __restrict__ qw,
                             float* __restrict__ qb) {
    const int tid = threadIdx.x;
    if (blockIdx.x < 64) {
        const float scale = __int_as_float(maxes[0]) / QMAX;
        const int idx = blockIdx.x * 256 + tid;  // float4 index
        float4 f = ((const float4*)w)[idx];
        bf16x4 o;
        o[0] = (__bf16)(fminf(fmaxf(rintf(f.x / scale), -QMAX), QMAX) * scale);
        o[1] = (__bf16)(fminf(fmaxf(rintf(f.y / scale), -QMAX), QMAX) * scale);
        o[2] = (__bf16)(fminf(fmaxf(rintf(f.z / scale), -QMAX), QMAX) * scale);
        o[3] = (__bf16)(fminf(fmaxf(rintf(f.w / scale), -QMAX), QMAX) * scale);
        ((bf16x4*)qw)[idx] = o;
    } else {
        const float scale = __int_as_float(maxes[1]) / QMAX;
        qb[tid] = fminf(fmaxf(rintf(b[tid] / scale), -QMAX), QMAX) * scale;
    }
}

// GEMM: M-tile = 64 rows per block, full N = 256 per block (x read once).
// 4 waves/block; wave wv computes all 64 rows x cols [wv*64, wv*64+64).
// A: LDS bf16 64x(256+8 pad); B: global bf16 (L2-hot, 128 KB total).
__global__ __launch_bounds__(256, 2)
void gemm_kernel(const float* __restrict__ x,
                 const __bf16* __restrict__ qw,
                 const float* __restrict__ qb,
                 float* __restrict__ out) {
    __shared__ __align__(16) __bf16 As[64][264];  // +8 pad: rows shift 4 banks
    const int tid  = threadIdx.x;
    const int lane = tid & 63;
    const int wv   = tid >> 6;
    const float* xa = x + (size_t)blockIdx.x * (64 * 256);

    // ---- stage A tile (64x256 fp32 -> bf16 LDS), perfectly coalesced ----
    #pragma unroll
    for (int i = 0; i < 16; ++i) {
        const int e = i * 1024 + tid * 4;       // flat fp32 index in tile
        float4 f = *(const float4*)(xa + e);
        const int r = e >> 8, c = e & 255;
        bf16x4 o;
        o[0] = (__bf16)f.x; o[1] = (__bf16)f.y;
        o[2] = (__bf16)f.z; o[3] = (__bf16)f.w;
        *(bf16x4*)(&As[r][c]) = o;
    }
    __syncthreads();

    // ---- MFMA main loop: K=256 fully unrolled, 8 steps of 32 ----
    const int g  = lane >> 4;    // k-group 0..3
    const int r  = lane & 15;
    const int n0 = wv * 64;
    f32x4 acc[4][4] = {};
    #pragma unroll
    for (int s = 0; s < 8; ++s) {
        const int k0 = s * 32 + g * 8;
        bf16x8 bfrag[4], afrag[4];
        #pragma unroll
        for (int j = 0; j < 4; ++j)
            bfrag[j] = *(const bf16x8*)(qw + (size_t)(n0 + j * 16 + r) * 256 + k0);
        #pragma unroll
        for (int i = 0; i < 4; ++i)
            afrag[i] = *(const bf16x8*)(&As[i * 16 + r][k0]);
        #pragma unroll
        for (int i = 0; i < 4; ++i)
            #pragma unroll
            for (int j = 0; j < 4; ++j)
                acc[i][j] = __builtin_amdgcn_mfma_f32_16x16x32_bf16(
                    afrag[i], bfrag[j], acc[i][j], 0, 0, 0);
    }

    // ---- epilogue: + qb, store fp32 ----
    float qbv[4];
    #pragma unroll
    for (int j = 0; j < 4; ++j) qbv[j] = qb[n0 + j * 16 + r];

    #pragma unroll
    for (int i = 0; i < 4; ++i) {
        const size_t row0 = (size_t)blockIdx.x * 64 + i * 16 + g * 4;
        #pragma unroll
        for (int rg = 0; rg < 4; ++rg) {
            float* orow = out + (row0 + rg) * 256 + n0 + r;
            #pragma unroll
            for (int j = 0; j < 4; ++j)
                orow[j * 16] = acc[i][j][rg] + qbv[j];
        }
    }
}

extern "C" void kernel_launch(void* const* d_in, const int* in_sizes, int n_in,
                              void* d_out, int out_size, void* d_ws, size_t ws_size,
                              hipStream_t stream) {
    const float* x = (const float*)d_in[0];   // [524288, 256]
    const float* w = (const float*)d_in[1];   // [256, 256]
    const float* b = (const float*)d_in[2];   // [256]
    float* out = (float*)d_out;

    int*    maxes = (int*)d_ws;
    float*  qb    = (float*)((char*)d_ws + 16);
    __bf16* qw    = (__bf16*)((char*)d_ws + 2048);

    hipLaunchKernelGGL(init_ws_kernel, dim3(1), dim3(1), 0, stream, maxes);
    hipLaunchKernelGGL(absmax_kernel, dim3(65), dim3(256), 0, stream,
                       w, b, maxes, maxes + 1);
    hipLaunchKernelGGL(quant_kernel, dim3(65), dim3(256), 0, stream,
                       w, b, maxes, qw, qb);

    const int rows    = in_sizes[0] / 256;    // 524288
    const int mblocks = rows / 64;            // 8192
    hipLaunchKernelGGL(gemm_kernel, dim3(mblocks), dim3(256), 0, stream,
                       x, qw, qb, out);
}